// Round 4
// baseline (465.150 us; speedup 1.0000x reference)
//
#include <hip/hip_runtime.h>

// MultiheadCrossAttention: B=4, SQ=SK=2048, D=1024, H=16, HD=64.
// bf16 MFMA 16x16x32, fp32 accum. ws: [W16 8MB][q16 16MB][k16 16MB][vt16 16MB][o16 16MB]
//
// attn computes S^T = K·Q^T; C-layout col=q, row=key -> P frags live in registers
// (key->slot permutation baked into vt16 layout). l = P·ones via MFMA (C-layout
// matches O rows -> no transpose). K dbuf + V single buf, 2 barriers/tile, each
// drain covered by compute. Projections: A fp32 pipelined through registers
// (loads issued post-barrier, cvt+ds_write post-compute), B via global_load_lds.

typedef __bf16 bf16_t;
typedef __attribute__((ext_vector_type(2))) __bf16 bf16x2;
typedef __attribute__((ext_vector_type(4))) __bf16 bf16x4;
typedef __attribute__((ext_vector_type(8))) __bf16 bf16x8;
typedef __attribute__((ext_vector_type(4))) float f32x4;

#define MFMA16(a, b, c) __builtin_amdgcn_mfma_f32_16x16x32_bf16(a, b, c, 0, 0, 0)

__device__ __forceinline__ void gl_lds16(const void* g, void* l) {
  __builtin_amdgcn_global_load_lds(
      (const __attribute__((address_space(1))) unsigned int*)g,
      (__attribute__((address_space(3))) unsigned int*)l, 16, 0, 0);
}

__device__ __forceinline__ bf16x2 cvt_pk_bf16(float a, float b) {
#if __has_builtin(__builtin_amdgcn_cvt_pk_bf16_f32)
  return __builtin_amdgcn_cvt_pk_bf16_f32(a, b);
#else
  bf16x2 r;
  r[0] = (bf16_t)a;
  r[1] = (bf16_t)b;
  return r;
#endif
}

// ---------------- weight fp32 -> bf16 ----------------
__global__ void wconv_kernel(const float* __restrict__ Wq, const float* __restrict__ Wk,
                             const float* __restrict__ Wv, const float* __restrict__ Wo,
                             bf16_t* __restrict__ out) {
  const int m = blockIdx.y;
  const float* src = (m == 0) ? Wq : (m == 1) ? Wk : (m == 2) ? Wv : Wo;
  bf16_t* dst = out + (size_t)m * (1024 * 1024);
  const int idx = (blockIdx.x * 256 + threadIdx.x) * 4;
  float4 v = *(const float4*)(src + idx);
  bf16x4 pk;
  pk[0] = (bf16_t)v.x; pk[1] = (bf16_t)v.y; pk[2] = (bf16_t)v.z; pk[3] = (bf16_t)v.w;
  *(bf16x4*)(dst + idx) = pk;
}

// ------- fused q/k/v projections: C = A_f32[8192,1024] @ W^T + bias, z picks A/W/out -------
__global__ __launch_bounds__(256, 2) void proj_kernel(
    const float* __restrict__ Aq, const float* __restrict__ Ak, const float* __restrict__ Av,
    const bf16_t* __restrict__ W16,
    const float* __restrict__ bq, const float* __restrict__ bk, const float* __restrict__ bv,
    bf16_t* __restrict__ q16, bf16_t* __restrict__ k16, bf16_t* __restrict__ vt16) {
  __shared__ __align__(16) bf16_t As[2][8192];
  __shared__ __align__(16) bf16_t Bs[2][8192];

  const int z = blockIdx.z;
  const float* A = (z == 0) ? Aq : (z == 1) ? Ak : Av;
  const bf16_t* Bw = W16 + (size_t)z * 1048576;
  const float* bias = (z == 0) ? bq : (z == 1) ? bk : bv;

  const int tid = threadIdx.x;
  const int lane = tid & 63, wave = tid >> 6;
  const int fm = lane & 15, quad = lane >> 4;
  const int wr = wave >> 1, wc = wave & 1;
  const int m0 = blockIdx.x * 128, n0 = blockIdx.y * 128;

  f32x4 acc[4][4];
#pragma unroll
  for (int i = 0; i < 4; ++i)
#pragma unroll
    for (int j = 0; j < 4; ++j) acc[i][j] = f32x4{0.f, 0.f, 0.f, 0.f};

  float4 areg[4][2];
  auto loadA = [&](int ks) {
#pragma unroll
    for (int it = 0; it < 4; ++it) {
      const int fid = wave * 4 + it;
      const int row = (fid >> 1) * 16 + fm;
      const int col = (fid & 1) * 32 + quad * 8;
      const float* s = A + (size_t)(m0 + row) * 1024 + ks * 64 + col;
      areg[it][0] = *(const float4*)s;
      areg[it][1] = *(const float4*)(s + 4);
    }
  };
  auto writeA = [&](int buf) {
#pragma unroll
    for (int it = 0; it < 4; ++it) {
      const int fid = wave * 4 + it;
      bf16x8 pk;
      bf16x2* p2 = (bf16x2*)&pk;
      p2[0] = cvt_pk_bf16(areg[it][0].x, areg[it][0].y);
      p2[1] = cvt_pk_bf16(areg[it][0].z, areg[it][0].w);
      p2[2] = cvt_pk_bf16(areg[it][1].x, areg[it][1].y);
      p2[3] = cvt_pk_bf16(areg[it][1].z, areg[it][1].w);
      *(bf16x8*)(As[buf] + fid * 512 + lane * 8) = pk;
    }
  };
  auto dmaB = [&](int ks, int buf) {
#pragma unroll
    for (int it = 0; it < 4; ++it) {
      const int fid = wave * 4 + it;
      const int row = (fid >> 1) * 16 + fm;
      const int col = (fid & 1) * 32 + quad * 8;
      gl_lds16(Bw + (size_t)(n0 + row) * 1024 + ks * 64 + col, Bs[buf] + fid * 512);
    }
  };

  loadA(0);
  writeA(0);  // one cold stall
  dmaB(0, 0);

  for (int ks = 0; ks < 16; ++ks) {
    __syncthreads();  // drains dmaB(ks) [+ loadA(ks) regs consumed last iter]
    if (ks < 15) {
      loadA(ks + 1);           // issued now, waited in writeA AFTER compute
      dmaB(ks + 1, (ks + 1) & 1);  // drained at next barrier
    }
    const bf16_t* Ab = As[ks & 1];
    const bf16_t* Bb = Bs[ks & 1];
#pragma unroll
    for (int u = 0; u < 2; ++u) {
      bf16x8 af[4], bfr[4];
#pragma unroll
      for (int i = 0; i < 4; ++i)
        af[i] = *(const bf16x8*)(Ab + ((4 * wr + i) * 2 + u) * 512 + lane * 8);
#pragma unroll
      for (int j = 0; j < 4; ++j)
        bfr[j] = *(const bf16x8*)(Bb + ((4 * wc + j) * 2 + u) * 512 + lane * 8);
#pragma unroll
      for (int i = 0; i < 4; ++i)
#pragma unroll
        for (int j = 0; j < 4; ++j) acc[i][j] = MFMA16(af[i], bfr[j], acc[i][j]);
    }
    if (ks < 15) writeA((ks + 1) & 1);
  }

  float bval[4];
#pragma unroll
  for (int j = 0; j < 4; ++j) bval[j] = bias[n0 + wc * 64 + j * 16 + fm];

  bf16_t* outp = (z == 0) ? q16 : (z == 1) ? k16 : vt16;
#pragma unroll
  for (int i = 0; i < 4; ++i) {
#pragma unroll
    for (int j = 0; j < 4; ++j) {
      const int col = n0 + wc * 64 + j * 16 + fm;
#pragma unroll
      for (int r = 0; r < 4; ++r) {
        const int row = m0 + wr * 64 + i * 16 + quad * 4 + r;
        const float v = acc[i][j][r] + bval[j];
        if (z != 2) {
          outp[(size_t)row * 1024 + col] = (bf16_t)v;
        } else {
          // vt16 permuted: per (bh, t128) tile, frag-major (nt,c) x lane x j
          const int bb = row >> 11, sk = row & 2047;
          const int tt = sk >> 7, L128 = sk & 127;
          const int c = L128 >> 5, hf = (L128 >> 4) & 1;
          const int qd = (L128 >> 2) & 3, rr = L128 & 3;
          const int hh = col >> 6, hd = col & 63;
          const int nt = hd >> 4, fv = hd & 15;
          const size_t idx = (((size_t)(bb * 16 + hh)) << 17) + tt * 8192 +
                             (nt * 4 + c) * 512 + (qd * 16 + fv) * 8 + hf * 4 + rr;
          outp[idx] = (bf16_t)v;
        }
      }
    }
  }
}

// ------- output projection: C_f32 = A_bf16[8192,1024] @ W^T + bias -------
__global__ __launch_bounds__(256, 2) void oproj_kernel(
    const bf16_t* __restrict__ A, const bf16_t* __restrict__ Bw,
    const float* __restrict__ bias, float* __restrict__ outp) {
  __shared__ __align__(16) bf16_t As[2][8192];
  __shared__ __align__(16) bf16_t Bs[2][8192];

  const int tid = threadIdx.x;
  const int lane = tid & 63, wave = tid >> 6;
  const int fm = lane & 15, quad = lane >> 4;
  const int wr = wave >> 1, wc = wave & 1;
  const int m0 = blockIdx.x * 128, n0 = blockIdx.y * 128;

  f32x4 acc[4][4];
#pragma unroll
  for (int i = 0; i < 4; ++i)
#pragma unroll
    for (int j = 0; j < 4; ++j) acc[i][j] = f32x4{0.f, 0.f, 0.f, 0.f};

  auto stage = [&](int ks, int buf) {
#pragma unroll
    for (int it = 0; it < 4; ++it) {
      const int fid = wave * 4 + it;
      const int row = (fid >> 1) * 16 + fm;
      const int col = (fid & 1) * 32 + quad * 8;
      gl_lds16(A + (size_t)(m0 + row) * 1024 + ks * 64 + col, As[buf] + fid * 512);
      gl_lds16(Bw + (size_t)(n0 + row) * 1024 + ks * 64 + col, Bs[buf] + fid * 512);
    }
  };

  stage(0, 0);
  for (int ks = 0; ks < 16; ++ks) {
    __syncthreads();
    if (ks < 15) stage(ks + 1, (ks + 1) & 1);
    const bf16_t* Ab = As[ks & 1];
    const bf16_t* Bb = Bs[ks & 1];
#pragma unroll
    for (int u = 0; u < 2; ++u) {
      bf16x8 af[4], bfr[4];
#pragma unroll
      for (int i = 0; i < 4; ++i)
        af[i] = *(const bf16x8*)(Ab + ((4 * wr + i) * 2 + u) * 512 + lane * 8);
#pragma unroll
      for (int j = 0; j < 4; ++j)
        bfr[j] = *(const bf16x8*)(Bb + ((4 * wc + j) * 2 + u) * 512 + lane * 8);
#pragma unroll
      for (int i = 0; i < 4; ++i)
#pragma unroll
        for (int j = 0; j < 4; ++j) acc[i][j] = MFMA16(af[i], bfr[j], acc[i][j]);
    }
  }

  float bval[4];
#pragma unroll
  for (int j = 0; j < 4; ++j) bval[j] = bias[n0 + wc * 64 + j * 16 + fm];
#pragma unroll
  for (int i = 0; i < 4; ++i)
#pragma unroll
    for (int j = 0; j < 4; ++j) {
      const int col = n0 + wc * 64 + j * 16 + fm;
#pragma unroll
      for (int r = 0; r < 4; ++r) {
        const int row = m0 + wr * 64 + i * 16 + quad * 4 + r;
        outp[(size_t)row * 1024 + col] = acc[i][j][r] + bval[j];
      }
    }
}

// ---------------- flash attention ----------------
// grid (16 q-tiles, 64 bh), 256 thr, wave w owns q rows [w*32, w*32+32).
// Phases per tile: [barrier A] dmaV(t) | QK_t, softmax | [barrier B] dmaK(t+1),
// mask(t+1) | PV_t (+ l via ones-MFMA).
__global__ __launch_bounds__(256, 3) void attn_kernel(
    const bf16_t* __restrict__ q16, const bf16_t* __restrict__ k16,
    const bf16_t* __restrict__ vt16, const int* __restrict__ mask,
    bf16_t* __restrict__ o16) {
  __shared__ __align__(16) bf16_t Kb[2][8192];  // 16 KB each
  __shared__ __align__(16) bf16_t Vb[8192];     // 16 KB
  __shared__ float mb[2][128];

  const int tid = threadIdx.x;
  const int lane = tid & 63, wave = tid >> 6;
  const int fm = lane & 15, quad = lane >> 4;
  const int qt = blockIdx.x, bh = blockIdx.y;
  const int b = bh >> 4, h = bh & 15;
  const float SC = 0.125f * 1.44269504f;  // HD^-0.5 * log2(e)

  // Q -> registers (B-operand of S^T)
  bf16x8 aq[2][2];
#pragma unroll
  for (int i = 0; i < 2; ++i)
#pragma unroll
    for (int dc = 0; dc < 2; ++dc) {
      const int row = qt * 128 + (2 * wave + i) * 16 + fm;
      aq[i][dc] = *(const bf16x8*)(q16 + ((size_t)(b * 2048 + row)) * 1024 + h * 64 +
                                   dc * 32 + quad * 8);
    }

  auto dmaK = [&](int t, int buf) {
    const bf16_t* kb = k16 + ((size_t)(b * 2048 + t * 128)) * 1024 + h * 64;
#pragma unroll
    for (int s = 0; s < 4; ++s) {
      const int fid = wave * 4 + s;
      const int row = (fid >> 1) * 16 + fm;
      const int col = (fid & 1) * 32 + quad * 8;
      gl_lds16(kb + (size_t)row * 1024 + col, Kb[buf] + fid * 512);
    }
  };
  auto dmaV = [&](int t) {
    const bf16_t* vb = vt16 + ((size_t)bh << 17) + t * 8192;
#pragma unroll
    for (int s = 0; s < 4; ++s) {
      const int fid = wave * 4 + s;
      gl_lds16(vb + fid * 512 + lane * 8, Vb + fid * 512);
    }
  };
  auto stageM = [&](int t) {
    if (tid < 32) {
      int4 m4 = *(const int4*)(mask + b * 2048 + t * 128 + tid * 4);
      float4 f{m4.x ? 0.f : -1e30f, m4.y ? 0.f : -1e30f, m4.z ? 0.f : -1e30f,
               m4.w ? 0.f : -1e30f};
      *(float4*)&mb[t & 1][tid * 4] = f;
    }
  };

  f32x4 oacc[2][4];
#pragma unroll
  for (int i = 0; i < 2; ++i)
#pragma unroll
    for (int n = 0; n < 4; ++n) oacc[i][n] = f32x4{0.f, 0.f, 0.f, 0.f};
  f32x4 lacc[2] = {f32x4{0.f, 0.f, 0.f, 0.f}, f32x4{0.f, 0.f, 0.f, 0.f}};
  bf16x8 ones;
#pragma unroll
  for (int e = 0; e < 8; ++e) ones[e] = (bf16_t)1.0f;

  dmaK(0, 0);
  stageM(0);

  for (int t = 0; t < 16; ++t) {
    __syncthreads();  // A: PV_{t-1} done; K_t + mask_t drained/visible
    dmaV(t);          // drained at barrier B, hidden by QK+softmax
    const bf16_t* K = Kb[t & 1];

    f32x4 sacc[2][8];
#pragma unroll
    for (int i = 0; i < 2; ++i)
#pragma unroll
      for (int j = 0; j < 8; ++j) sacc[i][j] = f32x4{0.f, 0.f, 0.f, 0.f};
#pragma unroll
    for (int j = 0; j < 8; ++j) {
#pragma unroll
      for (int dc = 0; dc < 2; ++dc) {
        bf16x8 kf = *(const bf16x8*)(K + (j * 2 + dc) * 512 + lane * 8);
        sacc[0][j] = MFMA16(kf, aq[0][dc], sacc[0][j]);
        sacc[1][j] = MFMA16(kf, aq[1][dc], sacc[1][j]);
      }
    }

    const float* mrow = mb[t & 1];
#pragma unroll
    for (int j = 0; j < 8; ++j) {
      f32x4 md = *(const f32x4*)&mrow[j * 16 + quad * 4];
#pragma unroll
      for (int i = 0; i < 2; ++i)
#pragma unroll
        for (int r = 0; r < 4; ++r)
          sacc[i][j][r] = __builtin_amdgcn_exp2f(fmaf(sacc[i][j][r], SC, md[r]));
    }
    __syncthreads();  // B: V_t drained; K_t reads done
    if (t < 15) {
      dmaK(t + 1, (t + 1) & 1);  // drained at next barrier A, hidden by PV
      stageM(t + 1);
    }

#pragma unroll
    for (int c = 0; c < 4; ++c) {
      bf16x8 pf[2];
#pragma unroll
      for (int i = 0; i < 2; ++i) {
        bf16x2* p2 = (bf16x2*)&pf[i];
        p2[0] = cvt_pk_bf16(sacc[i][2 * c][0], sacc[i][2 * c][1]);
        p2[1] = cvt_pk_bf16(sacc[i][2 * c][2], sacc[i][2 * c][3]);
        p2[2] = cvt_pk_bf16(sacc[i][2 * c + 1][0], sacc[i][2 * c + 1][1]);
        p2[3] = cvt_pk_bf16(sacc[i][2 * c + 1][2], sacc[i][2 * c + 1][3]);
      }
#pragma unroll
      for (int n = 0; n < 4; ++n) {
        bf16x8 vv = *(const bf16x8*)(Vb + (n * 4 + c) * 512 + lane * 8);
        oacc[0][n] = MFMA16(pf[0], vv, oacc[0][n]);
        oacc[1][n] = MFMA16(pf[1], vv, oacc[1][n]);
      }
      lacc[0] = MFMA16(pf[0], ones, lacc[0]);
      lacc[1] = MFMA16(pf[1], ones, lacc[1]);
    }
  }

  // epilogue: l is already in C-layout (rows quad*4+r) — normalize & store
#pragma unroll
  for (int i = 0; i < 2; ++i) {
#pragma unroll
    for (int r = 0; r < 4; ++r) {
      const float inv = 1.0f / lacc[i][r];
      const int row = qt * 128 + wave * 32 + i * 16 + quad * 4 + r;
#pragma unroll
      for (int n = 0; n < 4; ++n) {
        o16[((size_t)(b * 2048 + row)) * 1024 + h * 64 + n * 16 + fm] =
            (bf16_t)(oacc[i][n][r] * inv);
      }
    }
  }
}

// ---------------- launch ----------------
extern "C" void kernel_launch(void* const* d_in, const int* in_sizes, int n_in,
                              void* d_out, int out_size, void* d_ws, size_t ws_size,
                              hipStream_t stream) {
  const float* query = (const float*)d_in[0];
  const float* key   = (const float*)d_in[1];
  const float* value = (const float*)d_in[2];
  const int* mask    = (const int*)d_in[3];
  const float* Wq = (const float*)d_in[4];
  const float* bq = (const float*)d_in[5];
  const float* Wk = (const float*)d_in[6];
  const float* bk = (const float*)d_in[7];
  const float* Wv = (const float*)d_in[8];
  const float* bv = (const float*)d_in[9];
  const float* Wo = (const float*)d_in[10];
  const float* bo = (const float*)d_in[11];

  char* ws = (char*)d_ws;
  bf16_t* W16  = (bf16_t*)ws;
  bf16_t* q16  = (bf16_t*)(ws + (size_t)8 * 1024 * 1024);
  bf16_t* k16  = q16 + 8388608;
  bf16_t* vt16 = k16 + 8388608;
  bf16_t* o16  = vt16 + 8388608;

  wconv_kernel<<<dim3(1024, 4), 256, 0, stream>>>(Wq, Wk, Wv, Wo, W16);
  proj_kernel<<<dim3(64, 8, 3), 256, 0, stream>>>(query, key, value, W16, bq, bk, bv,
                                                  q16, k16, vt16);
  attn_kernel<<<dim3(16, 64), 256, 0, stream>>>(q16, k16, vt16, mask, o16);
  oproj_kernel<<<dim3(64, 8), 256, 0, stream>>>(o16, W16 + 3145728, bo, (float*)d_out);
}